// Round 1
// baseline (1197.983 us; speedup 1.0000x reference)
//
#include <hip/hip_runtime.h>

#define BB 128   // batch
#define TT 512   // time
#define EE 100   // embed dim
#define HH 128   // hidden
#define G4 512   // 4*H
#define KK 12    // tags

// ---------------------------------------------------------------------------
// Kernel 1: pregates  P[t][b][g] = bih[g]+bhh[g] + sum_e embed[sent[b,t],e]*Wih[g,e]
// grid = T blocks, 512 threads (one per gate column g)
// ---------------------------------------------------------------------------
__global__ __launch_bounds__(512, 2) void pregates_kernel(
    const int* __restrict__ sent, const float* __restrict__ embed,
    const float* __restrict__ Wih, const float* __restrict__ bih,
    const float* __restrict__ bhh, float* __restrict__ P)
{
  __shared__ __align__(16) float4 xt[BB][EE / 4];   // 128 x 25 float4 = 51.2 KB
  const int t = blockIdx.x;
  const int g = threadIdx.x;

  // cooperative gather of the 128 embedding rows for this timestep
  for (int idx = threadIdx.x; idx < BB * (EE / 4); idx += 512) {
    int r = idx / (EE / 4);
    int k = idx - r * (EE / 4);
    const float4* src =
        reinterpret_cast<const float4*>(embed + (size_t)sent[r * TT + t] * EE);
    xt[r][k] = src[k];
  }

  // Wih row for this gate column in registers (25 float4 = 100 VGPR)
  float4 w[EE / 4];
  const float4* wrow = reinterpret_cast<const float4*>(Wih + (size_t)g * EE);
  #pragma unroll
  for (int k = 0; k < EE / 4; ++k) w[k] = wrow[k];
  const float bias = bih[g] + bhh[g];
  __syncthreads();

  float* out = P + ((size_t)t * BB) * G4 + g;
  for (int r = 0; r < BB; r += 2) {
    float a0 = 0.f, b0 = 0.f, a1 = 0.f, b1 = 0.f;
    #pragma unroll
    for (int k = 0; k < EE / 4; ++k) {
      float4 e0 = xt[r][k];
      float4 e1 = xt[r + 1][k];
      a0 += w[k].x * e0.x + w[k].y * e0.y;
      b0 += w[k].z * e0.z + w[k].w * e0.w;
      a1 += w[k].x * e1.x + w[k].y * e1.y;
      b1 += w[k].z * e1.z + w[k].w * e1.w;
    }
    out[(size_t)r * G4]       = bias + a0 + b0;
    out[(size_t)(r + 1) * G4] = bias + a1 + b1;
  }
}

// ---------------------------------------------------------------------------
// Kernel 2: per-batch sequential LSTM + emissions + Viterbi + backtrace
// grid = B blocks (one per batch element), 512 threads (one per gate element)
// ---------------------------------------------------------------------------
__device__ __forceinline__ float sigf(float x) { return 1.f / (1.f + expf(-x)); }

__global__ __launch_bounds__(512, 2) void lstm_crf_kernel(
    const float* __restrict__ P, const float* __restrict__ Whh,
    const float* __restrict__ h0, const float* __restrict__ c0,
    const float* __restrict__ Wtag, const float* __restrict__ btag,
    const float* __restrict__ trans, float* __restrict__ out)
{
  __shared__ __align__(16) float h_lds[HH];
  __shared__ float gates[G4];
  __shared__ float vit[KK];
  __shared__ unsigned char bp[TT * KK];   // 6144 B, backpointers stay in LDS
  __shared__ int path[TT];

  const int b   = blockIdx.x;
  const int tid = threadIdx.x;

  // Whh row for this gate element in registers (32 float4 = 128 VGPR)
  float4 w[HH / 4];
  const float4* wrow = reinterpret_cast<const float4*>(Whh + (size_t)tid * HH);
  #pragma unroll
  for (int k = 0; k < HH / 4; ++k) w[k] = wrow[k];

  float c = 0.f;
  if (tid < HH) {
    c = c0[b * HH + tid];
    h_lds[tid] = h0[b * HH + tid];
  }

  // emission lanes: 12 tags x 32 lanes = 384 threads
  const int j = tid >> 5, l = tid & 31;
  const bool em   = (tid < KK * 32);
  const bool lead = em && (l == 0);
  float wt0 = 0.f, wt1 = 0.f, wt2 = 0.f, wt3 = 0.f, bt = 0.f;
  float tr[KK];
  #pragma unroll
  for (int i = 0; i < KK; ++i) tr[i] = 0.f;
  if (em) {
    wt0 = Wtag[j * HH + l];
    wt1 = Wtag[j * HH + l + 32];
    wt2 = Wtag[j * HH + l + 64];
    wt3 = Wtag[j * HH + l + 96];
  }
  if (lead) {
    bt = btag[j];
    #pragma unroll
    for (int i = 0; i < KK; ++i) tr[i] = trans[i * KK + j];  // column j
  }
  __syncthreads();

  const float* Pb = P + (size_t)b * G4 + tid;

  for (int t = 0; t < TT; ++t) {
    // --- phase 1: gate g = P[t][b][g] + Whh[g,:] . h ---
    float acc0 = 0.f, acc1 = 0.f, acc2 = 0.f, acc3 = 0.f;
    const float4* h4 = reinterpret_cast<const float4*>(h_lds);
    #pragma unroll
    for (int k = 0; k < HH / 4; k += 2) {
      float4 hv0 = h4[k], hv1 = h4[k + 1];
      acc0 += w[k].x * hv0.x + w[k].y * hv0.y;
      acc1 += w[k].z * hv0.z + w[k].w * hv0.w;
      acc2 += w[k + 1].x * hv1.x + w[k + 1].y * hv1.y;
      acc3 += w[k + 1].z * hv1.z + w[k + 1].w * hv1.w;
    }
    float gv = Pb[(size_t)t * BB * G4] + ((acc0 + acc1) + (acc2 + acc3));
    gates[tid] = gv;
    __syncthreads();  // B1

    // --- phase 2: cell update (threads 0..127) ---
    if (tid < HH) {
      float ig = gates[tid];
      float fg = gates[tid + HH];
      float gg = gates[tid + 2 * HH];
      float og = gates[tid + 3 * HH];
      c = sigf(fg) * c + sigf(ig) * tanhf(gg);
      h_lds[tid] = sigf(og) * tanhf(c);
    }
    __syncthreads();  // B2

    // --- phase 3: emissions (384 threads) + Viterbi (12 leaders) ---
    float newv = 0.f;
    int bi = 0;
    if (em) {
      float p = h_lds[l] * wt0 + h_lds[l + 32] * wt1 +
                h_lds[l + 64] * wt2 + h_lds[l + 96] * wt3;
      p += __shfl_xor(p, 16);
      p += __shfl_xor(p, 8);
      p += __shfl_xor(p, 4);
      p += __shfl_xor(p, 2);
      p += __shfl_xor(p, 1);
      if (lead) {
        float e = p + bt;
        if (t == 0) {
          newv = e;
        } else {
          float best = -1e30f;
          #pragma unroll
          for (int i = 0; i < KK; ++i) {
            float v = vit[i] + tr[i];
            if (v > best) { best = v; bi = i; }   // strict > => first max (jnp.argmax)
          }
          newv = e + best;
          bp[t * KK + j] = (unsigned char)bi;
        }
      }
    }
    __syncthreads();  // B3
    if (lead) vit[j] = newv;
    // next iteration's B1/B2 separate this write from the next phase-3 reads
  }
  __syncthreads();

  // --- backtrace (serial, LDS-resident) ---
  if (tid == 0) {
    float best = -1e30f;
    int tag = 0;
    for (int jj = 0; jj < KK; ++jj) {
      float v = vit[jj];
      if (v > best) { best = v; tag = jj; }
    }
    out[b] = best;            // scores
    path[TT - 1] = tag;
    for (int t = TT - 1; t >= 1; --t) {
      tag = bp[t * KK + tag];
      path[t - 1] = tag;
    }
  }
  __syncthreads();

  // paths out, coalesced: out[B + b*T + t] as float
  out[BB + (size_t)b * TT + tid] = (float)path[tid];
}

// ---------------------------------------------------------------------------
extern "C" void kernel_launch(void* const* d_in, const int* in_sizes, int n_in,
                              void* d_out, int out_size, void* d_ws, size_t ws_size,
                              hipStream_t stream) {
  const int*   sent  = (const int*)d_in[0];
  const float* h0    = (const float*)d_in[1];
  const float* c0    = (const float*)d_in[2];
  const float* embed = (const float*)d_in[3];
  const float* Wih   = (const float*)d_in[4];
  const float* Whh   = (const float*)d_in[5];
  const float* bih   = (const float*)d_in[6];
  const float* bhh   = (const float*)d_in[7];
  const float* Wtag  = (const float*)d_in[8];
  const float* btag  = (const float*)d_in[9];
  const float* trans = (const float*)d_in[10];
  float* out = (float*)d_out;
  float* P   = (float*)d_ws;   // [T][B][4H] fp32 = 2^27 bytes

  pregates_kernel<<<TT, 512, 0, stream>>>(sent, embed, Wih, bih, bhh, P);
  lstm_crf_kernel<<<BB, 512, 0, stream>>>(P, Whh, h0, c0, Wtag, btag, trans, out);
}

// Round 2
// 961.346 us; speedup vs baseline: 1.2462x; 1.2462x over previous
//
#include <hip/hip_runtime.h>

#define BB 128   // batch
#define TT 512   // time
#define EE 100   // embed dim
#define HH 128   // hidden
#define G4 512   // 4*H
#define KK 12    // tags

// ---------------------------------------------------------------------------
// Kernel 1: pregates  P2[t][b][e*4+r] = bih[g]+bhh[g] + sum_e' x[b,t,e']*Wih[g,e']
// where g = r*128+e  (gate-quad-interleaved layout so kernel 2 loads float4)
// grid = T blocks, 512 threads (thread owns output position tid = e*4+r)
// ---------------------------------------------------------------------------
__global__ __launch_bounds__(512, 2) void pregates_kernel(
    const int* __restrict__ sent, const float* __restrict__ embed,
    const float* __restrict__ Wih, const float* __restrict__ bih,
    const float* __restrict__ bhh, float* __restrict__ P)
{
  __shared__ __align__(16) float4 xt[BB][EE / 4];   // 128 x 25 float4 = 51.2 KB
  const int t = blockIdx.x;
  // output position tid = e*4 + r  ->  weight column g = r*128 + e
  const int g = ((threadIdx.x & 3) << 7) | (threadIdx.x >> 2);

  for (int idx = threadIdx.x; idx < BB * (EE / 4); idx += 512) {
    int r = idx / (EE / 4);
    int k = idx - r * (EE / 4);
    const float4* src =
        reinterpret_cast<const float4*>(embed + (size_t)sent[r * TT + t] * EE);
    xt[r][k] = src[k];
  }

  float4 w[EE / 4];
  const float4* wrow = reinterpret_cast<const float4*>(Wih + (size_t)g * EE);
  #pragma unroll
  for (int k = 0; k < EE / 4; ++k) w[k] = wrow[k];
  const float bias = bih[g] + bhh[g];
  __syncthreads();

  float* outp = P + ((size_t)t * BB) * G4 + threadIdx.x;   // contiguous writes
  for (int r = 0; r < BB; r += 2) {
    float a0 = 0.f, b0 = 0.f, a1 = 0.f, b1 = 0.f;
    #pragma unroll
    for (int k = 0; k < EE / 4; ++k) {
      float4 e0 = xt[r][k];
      float4 e1 = xt[r + 1][k];
      a0 += w[k].x * e0.x + w[k].y * e0.y;
      b0 += w[k].z * e0.z + w[k].w * e0.w;
      a1 += w[k].x * e1.x + w[k].y * e1.y;
      b1 += w[k].z * e1.z + w[k].w * e1.w;
    }
    outp[(size_t)r * G4]       = bias + a0 + b0;
    outp[(size_t)(r + 1) * G4] = bias + a1 + b1;
  }
}

// ---------------------------------------------------------------------------
// Kernel 2: per-batch sequential LSTM + emissions + Viterbi + backtrace
// grid = B blocks, 1024 threads. Thread = (e = tid>>3, chunk = tid&7).
// Each thread: Whh slab [4 gates][16 h-elems] in 64 VGPRs; reads its 16-float
// h chunk from LDS (padded, conflict-free); 8-lane shfl butterfly combines.
// Cell update done redundantly in all 8 chunk lanes (gates never hit LDS).
// ---------------------------------------------------------------------------
__device__ __forceinline__ float sigf(float x) { return 1.f / (1.f + expf(-x)); }

__global__ __launch_bounds__(1024, 4) void lstm_crf_kernel(
    const float* __restrict__ P, const float* __restrict__ Whh,
    const float* __restrict__ h0, const float* __restrict__ c0,
    const float* __restrict__ Wtag, const float* __restrict__ btag,
    const float* __restrict__ trans, float* __restrict__ out)
{
  // h padded: chunk c occupies floats [c*20, c*20+16) -> float4 index c*5+kq
  __shared__ __align__(16) float h_lds[8 * 20];
  __shared__ __align__(16) float trT[KK * 16];     // trT[j*16+i] = trans[i][j]
  __shared__ __align__(16) float vitbuf[2][16];    // double-buffered trellis
  __shared__ unsigned char bp[TT * KK];            // backpointers, 6 KB
  __shared__ int path[TT];

  const int b     = blockIdx.x;
  const int tid   = threadIdx.x;
  const int chunk = tid & 7;
  const int e     = tid >> 3;

  // Whh slab: w[r][kq] = Whh[r*128+e][chunk*16 + kq*4 .. +3]
  float4 w[4][4];
  #pragma unroll
  for (int r = 0; r < 4; ++r) {
    const float4* row = reinterpret_cast<const float4*>(
        Whh + (size_t)(r * HH + e) * HH + chunk * 16);
    #pragma unroll
    for (int kq = 0; kq < 4; ++kq) w[r][kq] = row[kq];
  }

  float c = c0[b * HH + e];   // replicated across the 8 chunk lanes

  if (tid < HH) h_lds[((tid >> 4) * 20) + (tid & 15)] = h0[b * HH + tid];
  if (tid < KK * KK) {
    int i = tid / KK, jj = tid - i * KK;
    trT[jj * 16 + i] = trans[tid];
  }

  // emission lanes: 12 tags x 32 lanes (waves 0..5)
  const int j = tid >> 5, l = tid & 31;
  float wt0 = 0.f, wt1 = 0.f, wt2 = 0.f, wt3 = 0.f, bt = 0.f;
  if (tid < KK * 32) {
    wt0 = Wtag[j * HH + l];
    wt1 = Wtag[j * HH + l + 32];
    wt2 = Wtag[j * HH + l + 64];
    wt3 = Wtag[j * HH + l + 96];
    bt  = btag[j];
  }
  __syncthreads();

  const float4* P4 = reinterpret_cast<const float4*>(P);
  const size_t pbase = (size_t)b * (G4 / 4) + e;
  float4 pc = P4[pbase];   // t = 0

  const float4* h4 = reinterpret_cast<const float4*>(h_lds);

  for (int t = 0; t < TT; ++t) {
    // --- phase 1: partial dots over this thread's 16-float h chunk ---
    float4 hv0 = h4[chunk * 5 + 0];
    float4 hv1 = h4[chunk * 5 + 1];
    float4 hv2 = h4[chunk * 5 + 2];
    float4 hv3 = h4[chunk * 5 + 3];
    float4 s0 = w[0][0] * hv0 + w[0][1] * hv1 + w[0][2] * hv2 + w[0][3] * hv3;
    float4 s1 = w[1][0] * hv0 + w[1][1] * hv1 + w[1][2] * hv2 + w[1][3] * hv3;
    float4 s2 = w[2][0] * hv0 + w[2][1] * hv1 + w[2][2] * hv2 + w[2][3] * hv3;
    float4 s3 = w[3][0] * hv0 + w[3][1] * hv1 + w[3][2] * hv2 + w[3][3] * hv3;
    float a0 = (s0.x + s0.y) + (s0.z + s0.w);
    float a1 = (s1.x + s1.y) + (s1.z + s1.w);
    float a2 = (s2.x + s2.y) + (s2.z + s2.w);
    float a3 = (s3.x + s3.y) + (s3.z + s3.w);
    #pragma unroll
    for (int d = 1; d < 8; d <<= 1) {
      a0 += __shfl_xor(a0, d);
      a1 += __shfl_xor(a1, d);
      a2 += __shfl_xor(a2, d);
      a3 += __shfl_xor(a3, d);
    }
    float gi = a0 + pc.x, gf = a1 + pc.y, gg = a2 + pc.z, go = a3 + pc.w;

    // prefetch next step's pregate quad (L2/L3 resident)
    float4 pn = P4[(size_t)(t + 1 < TT ? t + 1 : t) * BB * (G4 / 4) + pbase];

    // --- phase 2: cell update, redundant in all 8 chunk lanes ---
    c = sigf(gf) * c + sigf(gi) * tanhf(gg);
    float hval = sigf(go) * tanhf(c);

    __syncthreads();                                   // B1: old-h reads done
    if (chunk == 0) h_lds[((e >> 4) * 20) + (e & 15)] = hval;
    __syncthreads();                                   // B2: new h visible

    // --- phase 3: emissions (waves 0..5) + Viterbi (12 leaders) ---
    if (tid < KK * 32) {
      int idx = ((l >> 4) * 20) + (l & 15);
      float p = h_lds[idx] * wt0 + h_lds[idx + 40] * wt1 +
                h_lds[idx + 80] * wt2 + h_lds[idx + 120] * wt3;
      p += __shfl_xor(p, 16);
      p += __shfl_xor(p, 8);
      p += __shfl_xor(p, 4);
      p += __shfl_xor(p, 2);
      p += __shfl_xor(p, 1);
      if (l == 0) {
        float emi = p + bt;
        float nv;
        if (t > 0) {
          const float4* vv = reinterpret_cast<const float4*>(vitbuf[(t & 1) ^ 1]);
          const float4* tt4 = reinterpret_cast<const float4*>(trT + j * 16);
          float4 v0 = vv[0], v1 = vv[1], v2 = vv[2];
          float4 t0 = tt4[0], t1 = tt4[1], t2 = tt4[2];
          float cand[12] = {v0.x + t0.x, v0.y + t0.y, v0.z + t0.z, v0.w + t0.w,
                            v1.x + t1.x, v1.y + t1.y, v1.z + t1.z, v1.w + t1.w,
                            v2.x + t2.x, v2.y + t2.y, v2.z + t2.z, v2.w + t2.w};
          float best = cand[0];
          int bi = 0;
          #pragma unroll
          for (int i = 1; i < KK; ++i)
            if (cand[i] > best) { best = cand[i]; bi = i; }   // first-max
          nv = emi + best;
          bp[t * KK + j] = (unsigned char)bi;
        } else {
          nv = emi;
        }
        vitbuf[t & 1][j] = nv;
      }
    }
    pc = pn;
  }
  __syncthreads();

  // --- backtrace (serial, LDS-resident) ---
  if (tid == 0) {
    const float* vl = vitbuf[(TT - 1) & 1];
    float best = vl[0];
    int tag = 0;
    for (int jj = 1; jj < KK; ++jj)
      if (vl[jj] > best) { best = vl[jj]; tag = jj; }
    out[b] = best;                  // scores
    path[TT - 1] = tag;
    for (int t = TT - 1; t >= 1; --t) {
      tag = bp[t * KK + tag];
      path[t - 1] = tag;
    }
  }
  __syncthreads();

  if (tid < TT) out[BB + (size_t)b * TT + tid] = (float)path[tid];
}

// ---------------------------------------------------------------------------
extern "C" void kernel_launch(void* const* d_in, const int* in_sizes, int n_in,
                              void* d_out, int out_size, void* d_ws, size_t ws_size,
                              hipStream_t stream) {
  const int*   sent  = (const int*)d_in[0];
  const float* h0    = (const float*)d_in[1];
  const float* c0    = (const float*)d_in[2];
  const float* embed = (const float*)d_in[3];
  const float* Wih   = (const float*)d_in[4];
  const float* Whh   = (const float*)d_in[5];
  const float* bih   = (const float*)d_in[6];
  const float* bhh   = (const float*)d_in[7];
  const float* Wtag  = (const float*)d_in[8];
  const float* btag  = (const float*)d_in[9];
  const float* trans = (const float*)d_in[10];
  float* out = (float*)d_out;
  float* P   = (float*)d_ws;   // [T][B][4H] fp32, gate-quad-interleaved

  pregates_kernel<<<TT, 512, 0, stream>>>(sent, embed, Wih, bih, bhh, P);
  lstm_crf_kernel<<<BB, 1024, 0, stream>>>(P, Whh, h0, c0, Wtag, btag, trans, out);
}